// Round 3
// baseline (710.195 us; speedup 1.0000x reference)
//
#include <hip/hip_runtime.h>
#include <stdint.h>

#define NN 100000
#define NE 400000

typedef __attribute__((ext_vector_type(4))) float f32x4;
typedef __attribute__((ext_vector_type(8))) short bf16x8;

__device__ __forceinline__ short f2b(float x){
  union { float f; uint32_t u; } v; v.f = x;
  uint32_t r = v.u + 0x7FFFu + ((v.u >> 16) & 1u);
  return (short)(r >> 16);
}
__device__ __forceinline__ float b2f(short x){
  union { uint32_t u; float f; } v; v.u = ((uint32_t)(unsigned short)x) << 16; return v.f;
}
__device__ __forceinline__ bf16x8 pack_bf8(f32x4 a, f32x4 b){
  bf16x8 r;
  r[0]=f2b(a[0]); r[1]=f2b(a[1]); r[2]=f2b(a[2]); r[3]=f2b(a[3]);
  r[4]=f2b(b[0]); r[5]=f2b(b[1]); r[6]=f2b(b[2]); r[7]=f2b(b[3]);
  return r;
}

// 9 segments of 128x128, B-frag layout: dst[seg][kt*4096+g*1024+n*8+j] = bf16(W[koff+kt*32+g*8+j][n])
// 0 eW1[0:128](T_s) 1 eW1[128:256](T_r) 2 eW1[256:384] 3 eW2 4 eW3
// 5 nW1[0:128] 6 nW1[128:256] 7 nW2 8 nW3
__global__ void pack_all(const float* __restrict__ eW1, const float* __restrict__ eW2,
                         const float* __restrict__ eW3, const float* __restrict__ nW1,
                         const float* __restrict__ nW2, const float* __restrict__ nW3,
                         short* __restrict__ dst){
  int o = blockIdx.x*256 + threadIdx.x;
  int seg = o >> 14, rem = o & 16383;
  int kt = rem >> 12, g = (rem >> 10) & 3, n = (rem >> 3) & 127, j = rem & 7;
  int k = kt*32 + g*8 + j;
  const float* src = eW1; int koff = 0;
  switch(seg){
    case 0: src=eW1; koff=0;   break;
    case 1: src=eW1; koff=128; break;
    case 2: src=eW1; koff=256; break;
    case 3: src=eW2; break;
    case 4: src=eW3; break;
    case 5: src=nW1; koff=0;   break;
    case 6: src=nW1; koff=128; break;
    case 7: src=nW2; break;
    case 8: src=nW3; break;
  }
  dst[o] = f2b(src[(size_t)(koff+k)*128 + n]);
}

// T[node][0:128]=nodes@W1s, [128:256]=nodes@W1r  (bf16, no bias)
__global__ __launch_bounds__(512,4) void compute_T(
    const float* __restrict__ nodef, const short* __restrict__ wp,
    short* __restrict__ Tt, int nrows)
{
  __shared__ __align__(16) short Ws[16384];
  const int tid=threadIdx.x, lane=tid&63, wid=tid>>6, l16=lane&15, hi=lane>>4;
  const int row0 = blockIdx.x*128;
  const int arow_l = wid*16 + l16;
  const int arow_c = min(row0 + arow_l, nrows-1);
  const float* s = nodef + (size_t)arow_c*128;

  bf16x8 af[4];
  #pragma unroll
  for (int kt=0; kt<4; kt++){
    int ko = kt*32 + hi*8;
    af[kt] = pack_bf8(*(const f32x4*)(s+ko), *(const f32x4*)(s+ko+4));
  }
  int4 w[4];
  #pragma unroll
  for (int i=0;i<4;i++) w[i] = ((const int4*)wp)[tid + 512*i];

  for (int o=0; o<2; o++){
    if (o) __syncthreads();
    #pragma unroll
    for (int i=0;i<4;i++) ((int4*)Ws)[tid + 512*i] = w[i];
    if (o < 1){
      #pragma unroll
      for (int i=0;i<4;i++) w[i] = ((const int4*)(wp + 16384))[tid + 512*i];
    }
    __syncthreads();
    f32x4 acc[8];
    #pragma unroll
    for (int t=0;t<8;t++) acc[t] = (f32x4)(0.0f);
    #pragma unroll
    for (int kt=0;kt<4;kt++){
      #pragma unroll
      for (int t=0;t<8;t++){
        bf16x8 bw = *(const bf16x8*)&Ws[kt*4096 + hi*1024 + (t*16+l16)*8];
        acc[t] = __builtin_amdgcn_mfma_f32_16x16x32_bf16(af[kt], bw, acc[t], 0,0,0);
      }
    }
    #pragma unroll
    for (int t=0;t<8;t++){
      int col = t*16 + l16;
      #pragma unroll
      for (int r=0;r<4;r++){
        int row = row0 + wid*16 + hi*4 + r;
        if (row < nrows) Tt[(size_t)row*256 + o*128 + col] = f2b(acc[t][r]);
      }
    }
  }
}

// ---------------- CSR build ----------------
__global__ void count_edges(const int* __restrict__ rcv, int* __restrict__ counts){
  int e = blockIdx.x*256 + threadIdx.x;
  if (e < NE) atomicAdd(&counts[rcv[e]], 1);
}

__global__ __launch_bounds__(1024) void scan_offsets(const int* __restrict__ counts,
                                                     int* __restrict__ offsets,
                                                     int* __restrict__ cursor){
  __shared__ int ps[1024];
  const int t = threadIdx.x;
  const int per = (NN + 1023) / 1024;     // 98
  const int base = t * per;
  int s = 0;
  for (int i=0;i<per;i++){ int idx=base+i; if (idx<NN) s += counts[idx]; }
  ps[t] = s; __syncthreads();
  for (int d=1; d<1024; d<<=1){
    int v = (t>=d) ? ps[t-d] : 0;
    __syncthreads();
    ps[t] += v;
    __syncthreads();
  }
  int excl = (t==0) ? 0 : ps[t-1];
  for (int i=0;i<per;i++){
    int idx=base+i;
    if (idx<NN){ offsets[idx]=excl; cursor[idx]=excl; excl += counts[idx]; }
  }
  if (t==1023) offsets[NN] = excl;
}

__global__ void scatter_edges(const int* __restrict__ rcv, int* __restrict__ cursor,
                              int* __restrict__ eidx){
  int e = blockIdx.x*256 + threadIdx.x;
  if (e < NE){
    int p = atomicAdd(&cursor[rcv[e]], 1);
    eidx[p] = e;
  }
}

// MODE 0: edge MLP. L1 = edges@W1e + G(T_s[snd]+T_r[rcv]) + b1. Epilogue: out=LN+edge, Ey=bf16(LN)
// MODE 1: node MLP. L1 = nodes@W1a + agg@W1b + b1, agg = CSR-gather sum of Ey. out = LN+node
template<int MODE>
__global__ __launch_bounds__(512,4) void gnb_mlp(
    const float* __restrict__ nodef, const float* __restrict__ edgef,
    const int* __restrict__ snd, const int* __restrict__ rcv,
    const int* __restrict__ off, const int* __restrict__ eidx,
    const short* __restrict__ Tt, short* __restrict__ Ey,
    const short* __restrict__ Wp1a, const short* __restrict__ Wp1b,
    const short* __restrict__ Wp2, const short* __restrict__ Wp3,
    const float* __restrict__ b1p, const float* __restrict__ b2p, const float* __restrict__ b3p,
    const float* __restrict__ gmp, const float* __restrict__ btp,
    float* __restrict__ outp, int nrows)
{
  __shared__ __align__(16) short Ws[16384];   // one 128x128 bf16 weight, [kt][g][n][j]
  __shared__ __align__(16) short HGs[16384];  // [128][128] bf16, XOR-swizzled

  const int tid=threadIdx.x, lane=tid&63, wid=tid>>6, l16=lane&15, hi=lane>>4;
  const int row0 = blockIdx.x*128;
  const int arow_l = wid*16 + l16;
  const int arow_c = min(row0 + arow_l, nrows-1);

  // issue W1(a) stage loads early
  int4 w[4];
  #pragma unroll
  for (int i=0;i<4;i++) w[i] = ((const int4*)Wp1a)[tid + 512*i];

  if (MODE==0){
    // stage G = T_s[snd] + T_r[rcv] into HGs
    #pragma unroll
    for (int u=0;u<4;u++){
      int q = tid + u*512;
      int gr = q >> 4, c = q & 15;
      int grow = row0 + gr;                  // exact (NE % 128 == 0)
      int si = snd[grow], ri = rcv[grow];
      bf16x8 a = *(const bf16x8*)(Tt + (size_t)si*256 + c*8);
      bf16x8 b = *(const bf16x8*)(Tt + (size_t)ri*256 + 128 + c*8);
      bf16x8 o8;
      #pragma unroll
      for (int j=0;j<8;j++) o8[j] = f2b(b2f(a[j]) + b2f(b[j]));
      *(bf16x8*)((char*)HGs + gr*256 + ((c*16) ^ ((gr&7)<<4))) = o8;
    }
  } else {
    // stage agg = sum_{e in CSR[row]} Ey[e] into HGs
    #pragma unroll
    for (int u=0;u<4;u++){
      int q = tid + u*512;
      int gr = q >> 4, c = q & 15;
      int grow = row0 + gr;
      float a8[8] = {0,0,0,0,0,0,0,0};
      if (grow < nrows){
        int jb = off[grow], je = off[grow+1];
        for (int j=jb;j<je;j++){
          int e = eidx[j];
          bf16x8 v = *(const bf16x8*)(Ey + (size_t)e*128 + c*8);
          #pragma unroll
          for (int k=0;k<8;k++) a8[k] += b2f(v[k]);
        }
      }
      bf16x8 o8;
      #pragma unroll
      for (int k=0;k<8;k++) o8[k] = f2b(a8[k]);
      *(bf16x8*)((char*)HGs + gr*256 + ((c*16) ^ ((gr&7)<<4))) = o8;
    }
  }
  #pragma unroll
  for (int i=0;i<4;i++) ((int4*)Ws)[tid + 512*i] = w[i];
  #pragma unroll
  for (int i=0;i<4;i++) w[i] = ((const int4*)((MODE==1)?Wp1b:Wp2))[tid + 512*i];
  __syncthreads();

  f32x4 acc[8];
  #pragma unroll
  for (int t=0;t<8;t++) acc[t] = (f32x4)(0.0f);

  // ---- layer 1 (part a): A coalesced from global ----
  const float* s1 = (MODE==0) ? (edgef + (size_t)arow_c*128) : (nodef + (size_t)arow_c*128);
  #pragma unroll
  for (int kt=0;kt<4;kt++){
    int ko = kt*32 + hi*8;
    bf16x8 af = pack_bf8(*(const f32x4*)(s1+ko), *(const f32x4*)(s1+ko+4));
    #pragma unroll
    for (int t=0;t<8;t++){
      bf16x8 bw = *(const bf16x8*)&Ws[kt*4096 + hi*1024 + (t*16+l16)*8];
      acc[t] = __builtin_amdgcn_mfma_f32_16x16x32_bf16(af, bw, acc[t], 0,0,0);
    }
  }
  if (MODE==1){
    // ---- layer 1 (part b): A = agg from HGs, W = W1b ----
    __syncthreads();
    #pragma unroll
    for (int i=0;i<4;i++) ((int4*)Ws)[tid + 512*i] = w[i];
    #pragma unroll
    for (int i=0;i<4;i++) w[i] = ((const int4*)Wp2)[tid + 512*i];
    __syncthreads();
    #pragma unroll
    for (int kt=0;kt<4;kt++){
      bf16x8 af = *(const bf16x8*)((char*)HGs + arow_l*256 + ((kt*64 + hi*16) ^ ((arow_l&7)<<4)));
      #pragma unroll
      for (int t=0;t<8;t++){
        bf16x8 bw = *(const bf16x8*)&Ws[kt*4096 + hi*1024 + (t*16+l16)*8];
        acc[t] = __builtin_amdgcn_mfma_f32_16x16x32_bf16(af, bw, acc[t], 0,0,0);
      }
    }
  }
  // epi 1: (+G) + b1, relu -> HGs
  #pragma unroll
  for (int t=0;t<8;t++){
    int col = t*16 + l16;
    float bb = b1p[col];
    #pragma unroll
    for (int r=0;r<4;r++){
      int row = wid*16 + hi*4 + r;
      float g = 0.0f;
      if (MODE==0){
        g = b2f(*(const short*)((char*)HGs + row*256 + ((col*2) ^ ((row&7)<<4))));
      }
      float v = fmaxf(acc[t][r] + g + bb, 0.0f);
      *(short*)((char*)HGs + row*256 + ((col*2) ^ ((row&7)<<4))) = f2b(v);
      acc[t][r] = 0.0f;
    }
  }
  __syncthreads();
  #pragma unroll
  for (int i=0;i<4;i++) ((int4*)Ws)[tid + 512*i] = w[i];          // W2
  #pragma unroll
  for (int i=0;i<4;i++) w[i] = ((const int4*)Wp3)[tid + 512*i];   // preload W3
  __syncthreads();

  // ---- layer 2 ----
  #pragma unroll
  for (int kt=0;kt<4;kt++){
    bf16x8 af = *(const bf16x8*)((char*)HGs + arow_l*256 + ((kt*64 + hi*16) ^ ((arow_l&7)<<4)));
    #pragma unroll
    for (int t=0;t<8;t++){
      bf16x8 bw = *(const bf16x8*)&Ws[kt*4096 + hi*1024 + (t*16+l16)*8];
      acc[t] = __builtin_amdgcn_mfma_f32_16x16x32_bf16(af, bw, acc[t], 0,0,0);
    }
  }
  #pragma unroll
  for (int t=0;t<8;t++){
    float bb = b2p[t*16+l16];
    int col2 = (t*16+l16)*2;
    #pragma unroll
    for (int r=0;r<4;r++){
      float v = fmaxf(acc[t][r] + bb, 0.0f);
      int row = wid*16 + hi*4 + r;
      *(short*)((char*)HGs + row*256 + (col2 ^ ((row&7)<<4))) = f2b(v);
      acc[t][r] = 0.0f;
    }
  }
  __syncthreads();
  #pragma unroll
  for (int i=0;i<4;i++) ((int4*)Ws)[tid + 512*i] = w[i];          // W3
  __syncthreads();

  // ---- layer 3 ----
  #pragma unroll
  for (int kt=0;kt<4;kt++){
    bf16x8 af = *(const bf16x8*)((char*)HGs + arow_l*256 + ((kt*64 + hi*16) ^ ((arow_l&7)<<4)));
    #pragma unroll
    for (int t=0;t<8;t++){
      bf16x8 bw = *(const bf16x8*)&Ws[kt*4096 + hi*1024 + (t*16+l16)*8];
      acc[t] = __builtin_amdgcn_mfma_f32_16x16x32_bf16(af, bw, acc[t], 0,0,0);
    }
  }

  // ---- LayerNorm (in-register) + epilogue ----
  float ps[4] = {0,0,0,0}, pq[4] = {0,0,0,0};
  #pragma unroll
  for (int t=0;t<8;t++){
    float bb = b3p[t*16+l16];
    #pragma unroll
    for (int r=0;r<4;r++){
      float v = acc[t][r] + bb;
      acc[t][r] = v;
      ps[r] += v; pq[r] += v*v;
    }
  }
  #pragma unroll
  for (int m=1;m<16;m<<=1){
    #pragma unroll
    for (int r=0;r<4;r++){
      ps[r] += __shfl_xor(ps[r], m);
      pq[r] += __shfl_xor(pq[r], m);
    }
  }
  float mu[4], rs[4];
  #pragma unroll
  for (int r=0;r<4;r++){
    mu[r] = ps[r] * (1.0f/128.0f);
    float var = pq[r] * (1.0f/128.0f) - mu[r]*mu[r];
    rs[r] = rsqrtf(var + 1e-5f);
  }

  #pragma unroll
  for (int t=0;t<8;t++){
    int col = t*16 + l16;
    float gm = gmp[col], be = btp[col];
    #pragma unroll
    for (int r=0;r<4;r++){
      int erow = row0 + wid*16 + hi*4 + r;
      float y = (acc[t][r]-mu[r])*rs[r]*gm + be;
      if (MODE==0){
        size_t o = (size_t)erow*128 + col;
        outp[o] = y + edgef[o];
        Ey[o] = f2b(y);
      } else {
        if (erow < nrows){
          size_t o = (size_t)erow*128 + col;
          outp[o] = y + nodef[o];
        }
      }
    }
  }
}

extern "C" void kernel_launch(void* const* d_in, const int* in_sizes, int n_in,
                              void* d_out, int out_size, void* d_ws, size_t ws_size,
                              hipStream_t stream)
{
  (void)in_sizes; (void)n_in; (void)out_size; (void)ws_size;
  const float* nodef = (const float*)d_in[0];
  const float* edgef = (const float*)d_in[1];
  const int*   snd   = (const int*)d_in[2];
  const int*   rcv   = (const int*)d_in[3];
  const float* eW1 = (const float*)d_in[4];
  const float* eb1 = (const float*)d_in[5];
  const float* eW2 = (const float*)d_in[6];
  const float* eb2 = (const float*)d_in[7];
  const float* eW3 = (const float*)d_in[8];
  const float* eb3 = (const float*)d_in[9];
  const float* egm = (const float*)d_in[10];
  const float* ebt = (const float*)d_in[11];
  const float* nW1 = (const float*)d_in[12];
  const float* nb1 = (const float*)d_in[13];
  const float* nW2 = (const float*)d_in[14];
  const float* nb2 = (const float*)d_in[15];
  const float* nW3 = (const float*)d_in[16];
  const float* nb3 = (const float*)d_in[17];
  const float* ngm = (const float*)d_in[18];
  const float* nbt = (const float*)d_in[19];

  char* wsb = (char*)d_ws;
  short* Tt = (short*)wsb;                               // NN*256*2   = 51,200,000 B
  short* Ey = (short*)(wsb + (size_t)NN*256*2);          // NE*128*2   = 102,400,000 B
  int* counts  = (int*)(wsb + (size_t)NN*256*2 + (size_t)NE*128*2);
  int* offsets = counts + NN;                            // NN+16 ints (padded)
  int* cursor  = offsets + NN + 16;
  int* eidx    = cursor + NN;
  short* wp    = (short*)(eidx + NE);                    // 9*16384 shorts

  hipMemsetAsync(counts, 0, (size_t)NN*4, stream);
  count_edges<<<(NE+255)/256,256,0,stream>>>(rcv, counts);
  scan_offsets<<<1,1024,0,stream>>>(counts, offsets, cursor);
  scatter_edges<<<(NE+255)/256,256,0,stream>>>(rcv, cursor, eidx);

  pack_all<<<576,256,0,stream>>>(eW1,eW2,eW3,nW1,nW2,nW3,wp);
  compute_T<<<(NN+127)/128,512,0,stream>>>(nodef, wp, Tt, NN);

  float* out_nodes = (float*)d_out;
  float* out_edges = out_nodes + (size_t)NN*128;

  gnb_mlp<0><<<NE/128,512,0,stream>>>(nodef, edgef, snd, rcv, offsets, eidx, Tt, Ey,
      wp+2*16384, (const short*)nullptr, wp+3*16384, wp+4*16384,
      eb1,eb2,eb3, egm,ebt, out_edges, NE);
  gnb_mlp<1><<<(NN+127)/128,512,0,stream>>>(nodef, edgef, snd, rcv, offsets, eidx, Tt, Ey,
      wp+5*16384, wp+6*16384, wp+7*16384, wp+8*16384,
      nb1,nb2,nb3, ngm,nbt, out_nodes, NN);
}

// Round 4
// 560.211 us; speedup vs baseline: 1.2677x; 1.2677x over previous
//
#include <hip/hip_runtime.h>
#include <stdint.h>

#define NN 100000
#define NE 400000
#define SCAN_B 391   // ceil(NN/256)

typedef __attribute__((ext_vector_type(4))) float f32x4;
typedef __attribute__((ext_vector_type(8))) short bf16x8;

__device__ __forceinline__ short f2b(float x){
  union { float f; uint32_t u; } v; v.f = x;
  uint32_t r = v.u + 0x7FFFu + ((v.u >> 16) & 1u);
  return (short)(r >> 16);
}
__device__ __forceinline__ float b2f(short x){
  union { uint32_t u; float f; } v; v.u = ((uint32_t)(unsigned short)x) << 16; return v.f;
}
__device__ __forceinline__ bf16x8 pack_bf8(f32x4 a, f32x4 b){
  bf16x8 r;
  r[0]=f2b(a[0]); r[1]=f2b(a[1]); r[2]=f2b(a[2]); r[3]=f2b(a[3]);
  r[4]=f2b(b[0]); r[5]=f2b(b[1]); r[6]=f2b(b[2]); r[7]=f2b(b[3]);
  return r;
}

// 9 segments of 128x128, B-frag layout: dst[seg][kt*4096+g*1024+n*8+j] = bf16(W[koff+kt*32+g*8+j][n])
// 0 eW1[0:128](T_s) 1 eW1[128:256](T_r) 2 eW1[256:384] 3 eW2 4 eW3
// 5 nW1[0:128] 6 nW1[128:256] 7 nW2 8 nW3
__global__ void pack_all(const float* __restrict__ eW1, const float* __restrict__ eW2,
                         const float* __restrict__ eW3, const float* __restrict__ nW1,
                         const float* __restrict__ nW2, const float* __restrict__ nW3,
                         short* __restrict__ dst){
  int o = blockIdx.x*256 + threadIdx.x;
  int seg = o >> 14, rem = o & 16383;
  int kt = rem >> 12, g = (rem >> 10) & 3, n = (rem >> 3) & 127, j = rem & 7;
  int k = kt*32 + g*8 + j;
  const float* src = eW1; int koff = 0;
  switch(seg){
    case 0: src=eW1; koff=0;   break;
    case 1: src=eW1; koff=128; break;
    case 2: src=eW1; koff=256; break;
    case 3: src=eW2; break;
    case 4: src=eW3; break;
    case 5: src=nW1; koff=0;   break;
    case 6: src=nW1; koff=128; break;
    case 7: src=nW2; break;
    case 8: src=nW3; break;
  }
  dst[o] = f2b(src[(size_t)(koff+k)*128 + n]);
}

// ---------------- CSR build (parallel) ----------------
__global__ void k_count(const int* __restrict__ rcv, int* __restrict__ counts){
  int e = blockIdx.x*256 + threadIdx.x;
  if (e < NE) atomicAdd(&counts[rcv[e]], 1);
}
__global__ void k_psum(const int* __restrict__ counts, int* __restrict__ psums){
  __shared__ int red[256];
  int t = threadIdx.x, i = blockIdx.x*256 + t;
  red[t] = (i < NN) ? counts[i] : 0;
  __syncthreads();
  for (int d=128; d; d>>=1){ if (t<d) red[t] += red[t+d]; __syncthreads(); }
  if (!t) psums[blockIdx.x] = red[0];
}
__global__ __launch_bounds__(512) void k_scanp(const int* __restrict__ psums, int* __restrict__ bbase){
  __shared__ int ps[512];
  int t = threadIdx.x;
  int v = (t < SCAN_B) ? psums[t] : 0;
  ps[t] = v; __syncthreads();
  for (int d=1; d<512; d<<=1){
    int x = (t>=d) ? ps[t-d] : 0;
    __syncthreads();
    ps[t] += x;
    __syncthreads();
  }
  if (t < SCAN_B) bbase[t] = ps[t] - v;   // exclusive
}
__global__ void k_local(const int* __restrict__ counts, const int* __restrict__ bbase,
                        int* __restrict__ offsets, int* __restrict__ cursor){
  __shared__ int ps[256];
  int t = threadIdx.x, i = blockIdx.x*256 + t;
  int v = (i < NN) ? counts[i] : 0;
  ps[t] = v; __syncthreads();
  for (int d=1; d<256; d<<=1){
    int x = (t>=d) ? ps[t-d] : 0;
    __syncthreads();
    ps[t] += x;
    __syncthreads();
  }
  int excl = bbase[blockIdx.x] + ps[t] - v;
  if (i < NN){ offsets[i] = excl; cursor[i] = excl; }
  if (i == 0) offsets[NN] = NE;
}
__global__ void k_scatter(const int* __restrict__ rcv, int* __restrict__ cursor,
                          int* __restrict__ pos){
  int e = blockIdx.x*256 + threadIdx.x;
  if (e < NE) pos[e] = atomicAdd(&cursor[rcv[e]], 1);
}

// T[node][0:128]=nodes@W1s, [128:256]=nodes@W1r  (bf16, no bias), vectorized 16B stores
__global__ __launch_bounds__(512,4) void compute_T(
    const float* __restrict__ nodef, const short* __restrict__ wp,
    short* __restrict__ Tt, int nrows)
{
  __shared__ __align__(16) short Ws[16384];   // 32KB: weight, then reused as y-staging
  const int tid=threadIdx.x, lane=tid&63, wid=tid>>6, l16=lane&15, hi=lane>>4;
  const int row0 = blockIdx.x*128;
  const int arow_l = wid*16 + l16;
  const int arow_c = min(row0 + arow_l, nrows-1);
  const float* s = nodef + (size_t)arow_c*128;

  bf16x8 af[4];
  #pragma unroll
  for (int kt=0; kt<4; kt++){
    int ko = kt*32 + hi*8;
    af[kt] = pack_bf8(*(const f32x4*)(s+ko), *(const f32x4*)(s+ko+4));
  }
  int4 w[4];
  #pragma unroll
  for (int i=0;i<4;i++) w[i] = ((const int4*)wp)[tid + 512*i];

  for (int o=0; o<2; o++){
    if (o) __syncthreads();
    #pragma unroll
    for (int i=0;i<4;i++) ((int4*)Ws)[tid + 512*i] = w[i];
    if (o < 1){
      #pragma unroll
      for (int i=0;i<4;i++) w[i] = ((const int4*)(wp + 16384))[tid + 512*i];
    }
    __syncthreads();
    f32x4 acc[8];
    #pragma unroll
    for (int t=0;t<8;t++) acc[t] = (f32x4)(0.0f);
    #pragma unroll
    for (int kt=0;kt<4;kt++){
      #pragma unroll
      for (int t=0;t<8;t++){
        bf16x8 bw = *(const bf16x8*)&Ws[kt*4096 + hi*1024 + (t*16+l16)*8];
        acc[t] = __builtin_amdgcn_mfma_f32_16x16x32_bf16(af[kt], bw, acc[t], 0,0,0);
      }
    }
    __syncthreads();   // all waves done reading Ws; reuse as [128][128] bf16 staging
    #pragma unroll
    for (int t=0;t<8;t++){
      int col = t*16 + l16;
      #pragma unroll
      for (int r=0;r<4;r++){
        int row = wid*16 + hi*4 + r;
        *(short*)((char*)Ws + row*256 + ((col*2) ^ ((row&7)<<4))) = f2b(acc[t][r]);
      }
    }
    // wave-private readback -> 16B stores
    #pragma unroll
    for (int u=0;u<4;u++){
      int q = lane + u*64;
      int r16 = q >> 4, c = q & 15;
      int rl = wid*16 + r16;
      int grow = row0 + rl;
      if (grow < nrows){
        bf16x8 v = *(const bf16x8*)((char*)Ws + rl*256 + ((c*16) ^ ((rl&7)<<4)));
        *(bf16x8*)(Tt + (size_t)grow*256 + o*128 + c*8) = v;
      }
    }
  }
}

#define STAGE(NEXT) do{ __syncthreads(); \
  ((int4*)Ws)[tid]=wa0; ((int4*)Ws)[tid+512]=wa1; \
  wa0=((const int4*)(NEXT))[tid]; wa1=((const int4*)(NEXT))[tid+512]; \
  __syncthreads(); }while(0)
#define STAGE_LAST() do{ __syncthreads(); \
  ((int4*)Ws)[tid]=wa0; ((int4*)Ws)[tid+512]=wa1; \
  __syncthreads(); }while(0)
#define MMG(H) do{ _Pragma("unroll") for(int kk=0;kk<2;kk++){ int kt=(H)*2+kk; bf16x8 afv=afg[kt]; \
  _Pragma("unroll") for(int t=0;t<8;t++){ bf16x8 bw=*(const bf16x8*)&Ws[kk*4096+hi*1024+(t*16+l16)*8]; \
    acc[t]=__builtin_amdgcn_mfma_f32_16x16x32_bf16(afv,bw,acc[t],0,0,0);} } }while(0)
#define MMH(H) do{ _Pragma("unroll") for(int kk=0;kk<2;kk++){ int kt=(H)*2+kk; \
  bf16x8 afv=*(const bf16x8*)((char*)HGs+arow_l*256+((kt*64+hi*16)^((arow_l&7)<<4))); \
  _Pragma("unroll") for(int t=0;t<8;t++){ bf16x8 bw=*(const bf16x8*)&Ws[kk*4096+hi*1024+(t*16+l16)*8]; \
    acc[t]=__builtin_amdgcn_mfma_f32_16x16x32_bf16(afv,bw,acc[t],0,0,0);} } }while(0)
#define EPI_RELU(BP, ADDG) do{ \
  _Pragma("unroll") for (int t=0;t<8;t++){ \
    int col=t*16+l16; float bb=(BP)[col]; \
    _Pragma("unroll") for (int r=0;r<4;r++){ \
      int row=wid*16+hi*4+r; \
      float g=0.0f; \
      if (ADDG) g=b2f(*(const short*)((char*)HGs+row*256+((col*2)^((row&7)<<4)))); \
      float v=fmaxf(acc[t][r]+g+bb,0.0f); \
      *(short*)((char*)HGs+row*256+((col*2)^((row&7)<<4)))=f2b(v); \
      acc[t][r]=0.0f; \
    } } }while(0)

// MODE 0: edge MLP. L1 = edges@W1e + G(T_s[snd]+T_r[rcv]) + b1. out=LN+edge, Ey[pos[e]]=bf16(LN)
// MODE 1: node MLP. L1 = nodes@W1a + agg@W1b + b1; agg = contiguous CSR sum of Ey. out=LN+node
template<int MODE>
__global__ __launch_bounds__(512,6) void gnb_mlp(
    const float* __restrict__ nodef, const float* __restrict__ edgef,
    const int* __restrict__ snd, const int* __restrict__ rcv,
    const int* __restrict__ off, const int* __restrict__ pos,
    const short* __restrict__ Tt, short* __restrict__ Ey,
    const short* __restrict__ W1a, const short* __restrict__ W1b,
    const short* __restrict__ W2, const short* __restrict__ W3,
    const float* __restrict__ b1p, const float* __restrict__ b2p, const float* __restrict__ b3p,
    const float* __restrict__ gmp, const float* __restrict__ btp,
    float* __restrict__ outp, int nrows)
{
  __shared__ __align__(16) short Ws[8192];    // 16KB: half of one 128x128 weight (2 ktiles)
  __shared__ __align__(16) short HGs[16384];  // 32KB: [128][128] bf16, XOR-swizzled

  const int tid=threadIdx.x, lane=tid&63, wid=tid>>6, l16=lane&15, hi=lane>>4;
  const int row0 = blockIdx.x*128;
  const int arow_l = wid*16 + l16;
  const int arow_c = min(row0 + arow_l, nrows-1);

  int4 wa0 = ((const int4*)W1a)[tid];
  int4 wa1 = ((const int4*)W1a)[tid+512];

  // A-row preload (f32 -> bf16) for layer-1a
  const float* s1 = (MODE==0) ? (edgef + (size_t)arow_c*128) : (nodef + (size_t)arow_c*128);
  bf16x8 afg[4];
  #pragma unroll
  for (int kt=0;kt<4;kt++){
    int ko = kt*32 + hi*8;
    afg[kt] = pack_bf8(*(const f32x4*)(s1+ko), *(const f32x4*)(s1+ko+4));
  }

  if (MODE==0){
    // stage G = T_s[snd] + T_r[rcv] into HGs
    bf16x8 ga[4], gb[4];
    #pragma unroll
    for (int u=0;u<4;u++){
      int q = tid + u*512, gr = q >> 4, c = q & 15;
      int grow = row0 + gr;                  // exact (NE % 128 == 0)
      int si = snd[grow], ri = rcv[grow];
      ga[u] = *(const bf16x8*)(Tt + (size_t)si*256 + c*8);
      gb[u] = *(const bf16x8*)(Tt + (size_t)ri*256 + 128 + c*8);
    }
    #pragma unroll
    for (int u=0;u<4;u++){
      int q = tid + u*512, gr = q >> 4, c = q & 15;
      bf16x8 o8;
      #pragma unroll
      for (int j=0;j<8;j++) o8[j] = f2b(b2f(ga[u][j]) + b2f(gb[u][j]));
      *(bf16x8*)((char*)HGs + gr*256 + ((c*16) ^ ((gr&7)<<4))) = o8;
    }
  } else {
    // stage agg = contiguous CSR-stream sum of Ey rows
    #pragma unroll
    for (int u=0;u<4;u++){
      int q = tid + u*512, gr = q >> 4, c = q & 15;
      int grow = row0 + gr;
      float s8[8] = {0,0,0,0,0,0,0,0};
      if (grow < nrows){
        int jb = off[grow], je = off[grow+1];
        for (int j=jb;j<je;j++){
          bf16x8 v = *(const bf16x8*)(Ey + (size_t)j*128 + c*8);
          #pragma unroll
          for (int k=0;k<8;k++) s8[k] += b2f(v[k]);
        }
      }
      bf16x8 o8;
      #pragma unroll
      for (int k=0;k<8;k++) o8[k] = f2b(s8[k]);
      *(bf16x8*)((char*)HGs + gr*256 + ((c*16) ^ ((gr&7)<<4))) = o8;
    }
  }

  f32x4 acc[8];
  #pragma unroll
  for (int t=0;t<8;t++) acc[t] = (f32x4)(0.0f);

  if (MODE==0){
    STAGE(W1a+8192); MMG(0);
    STAGE(W2);       MMG(1); EPI_RELU(b1p, true);
    STAGE(W2+8192);  MMH(0);
    STAGE(W3);       MMH(1); EPI_RELU(b2p, false);
    STAGE(W3+8192);  MMH(0);
    STAGE_LAST();    MMH(1);
  } else {
    STAGE(W1a+8192); MMG(0);
    STAGE(W1b);      MMG(1);
    STAGE(W1b+8192); MMH(0);
    STAGE(W2);       MMH(1); EPI_RELU(b1p, false);
    STAGE(W2+8192);  MMH(0);
    STAGE(W3);       MMH(1); EPI_RELU(b2p, false);
    STAGE(W3+8192);  MMH(0);
    STAGE_LAST();    MMH(1);
  }

  // ---- LayerNorm (in-register) ----
  float ps[4] = {0,0,0,0}, pq[4] = {0,0,0,0};
  #pragma unroll
  for (int t=0;t<8;t++){
    float bb = b3p[t*16+l16];
    #pragma unroll
    for (int r=0;r<4;r++){
      float v = acc[t][r] + bb;
      acc[t][r] = v;
      ps[r] += v; pq[r] += v*v;
    }
  }
  #pragma unroll
  for (int m=1;m<16;m<<=1){
    #pragma unroll
    for (int r=0;r<4;r++){
      ps[r] += __shfl_xor(ps[r], m);
      pq[r] += __shfl_xor(pq[r], m);
    }
  }
  float mu[4], rs[4];
  #pragma unroll
  for (int r=0;r<4;r++){
    mu[r] = ps[r] * (1.0f/128.0f);
    float var = pq[r] * (1.0f/128.0f) - mu[r]*mu[r];
    rs[r] = rsqrtf(var + 1e-5f);
  }

  // ---- epilogue ----
  #pragma unroll
  for (int t=0;t<8;t++){
    int col = t*16 + l16;
    float gm = gmp[col], be = btp[col];
    #pragma unroll
    for (int r=0;r<4;r++){
      int erow = row0 + wid*16 + hi*4 + r;
      float y = (acc[t][r]-mu[r])*rs[r]*gm + be;
      if (MODE==0){
        size_t o = (size_t)erow*128 + col;
        outp[o] = y + edgef[o];
        int row = wid*16 + hi*4 + r;
        *(short*)((char*)HGs + row*256 + ((col*2) ^ ((row&7)<<4))) = f2b(y);
      } else {
        if (erow < nrows){
          size_t o = (size_t)erow*128 + col;
          outp[o] = y + nodef[o];
        }
      }
    }
  }
  if (MODE==0){
    // wave-private readback -> 16B CSR-ordered scatter (line-complete writes)
    #pragma unroll
    for (int u=0;u<4;u++){
      int q = lane + u*64;
      int r16 = q >> 4, c = q & 15;
      int rl = wid*16 + r16;
      int grow = row0 + rl;
      int p = pos[grow];
      bf16x8 v = *(const bf16x8*)((char*)HGs + rl*256 + ((c*16) ^ ((rl&7)<<4)));
      *(bf16x8*)(Ey + (size_t)p*128 + c*8) = v;
    }
  }
}

extern "C" void kernel_launch(void* const* d_in, const int* in_sizes, int n_in,
                              void* d_out, int out_size, void* d_ws, size_t ws_size,
                              hipStream_t stream)
{
  (void)in_sizes; (void)n_in; (void)out_size; (void)ws_size;
  const float* nodef = (const float*)d_in[0];
  const float* edgef = (const float*)d_in[1];
  const int*   snd   = (const int*)d_in[2];
  const int*   rcv   = (const int*)d_in[3];
  const float* eW1 = (const float*)d_in[4];
  const float* eb1 = (const float*)d_in[5];
  const float* eW2 = (const float*)d_in[6];
  const float* eb2 = (const float*)d_in[7];
  const float* eW3 = (const float*)d_in[8];
  const float* eb3 = (const float*)d_in[9];
  const float* egm = (const float*)d_in[10];
  const float* ebt = (const float*)d_in[11];
  const float* nW1 = (const float*)d_in[12];
  const float* nb1 = (const float*)d_in[13];
  const float* nW2 = (const float*)d_in[14];
  const float* nb2 = (const float*)d_in[15];
  const float* nW3 = (const float*)d_in[16];
  const float* nb3 = (const float*)d_in[17];
  const float* ngm = (const float*)d_in[18];
  const float* nbt = (const float*)d_in[19];

  char* wsb = (char*)d_ws;
  short* Tt = (short*)wsb;                               // NN*256*2
  short* Ey = (short*)(wsb + (size_t)NN*256*2);          // NE*128*2
  int* counts  = (int*)(wsb + (size_t)NN*256*2 + (size_t)NE*128*2);
  int* offsets = counts + NN;                            // NN+1
  int* cursor  = offsets + NN + 8;
  int* psums   = cursor + NN;                            // 512
  int* bbase   = psums + 512;                            // 512
  int* pos     = bbase + 512;                            // NE
  short* wp    = (short*)(pos + NE);                     // 9*16384 shorts

  hipMemsetAsync(counts, 0, (size_t)NN*4, stream);
  k_count<<<(NE+255)/256,256,0,stream>>>(rcv, counts);
  k_psum<<<SCAN_B,256,0,stream>>>(counts, psums);
  k_scanp<<<1,512,0,stream>>>(psums, bbase);
  k_local<<<SCAN_B,256,0,stream>>>(counts, bbase, offsets, cursor);
  k_scatter<<<(NE+255)/256,256,0,stream>>>(rcv, cursor, pos);

  pack_all<<<576,256,0,stream>>>(eW1,eW2,eW3,nW1,nW2,nW3,wp);
  compute_T<<<(NN+127)/128,512,0,stream>>>(nodef, wp, Tt, NN);

  float* out_nodes = (float*)d_out;
  float* out_edges = out_nodes + (size_t)NN*128;

  gnb_mlp<0><<<NE/128,512,0,stream>>>(nodef, edgef, snd, rcv, offsets, pos, Tt, Ey,
      wp+2*16384, (const short*)nullptr, wp+3*16384, wp+4*16384,
      eb1,eb2,eb3, egm,ebt, out_edges, NE);
  gnb_mlp<1><<<(NN+127)/128,512,0,stream>>>(nodef, edgef, snd, rcv, offsets, pos, Tt, Ey,
      wp+5*16384, wp+6*16384, wp+7*16384, wp+8*16384,
      nb1,nb2,nb3, ngm,nbt, out_nodes, NN);
}

// Round 5
// 440.306 us; speedup vs baseline: 1.6130x; 1.2723x over previous
//
#include <hip/hip_runtime.h>
#include <stdint.h>

#define NN 100000
#define NE 400000
#define SCAN_B 391   // ceil(NN/256)

typedef __attribute__((ext_vector_type(4))) float f32x4;
typedef __attribute__((ext_vector_type(8))) short bf16x8;

__device__ __forceinline__ short f2b(float x){
  union { float f; uint32_t u; } v; v.f = x;
  uint32_t r = v.u + 0x7FFFu + ((v.u >> 16) & 1u);
  return (short)(r >> 16);
}
__device__ __forceinline__ float b2f(short x){
  union { uint32_t u; float f; } v; v.u = ((uint32_t)(unsigned short)x) << 16; return v.f;
}
__device__ __forceinline__ bf16x8 pack_bf8(f32x4 a, f32x4 b){
  bf16x8 r;
  r[0]=f2b(a[0]); r[1]=f2b(a[1]); r[2]=f2b(a[2]); r[3]=f2b(a[3]);
  r[4]=f2b(b[0]); r[5]=f2b(b[1]); r[6]=f2b(b[2]); r[7]=f2b(b[3]);
  return r;
}

// 9 segments of 128x128, B-frag layout: dst[seg][kt*4096+g*1024+n*8+j] = bf16(W[koff+kt*32+g*8+j][n])
// 0 eW1[0:128](T_s) 1 eW1[128:256](T_r) 2 eW1[256:384] 3 eW2 4 eW3
// 5 nW1[0:128] 6 nW1[128:256] 7 nW2 8 nW3
__global__ void pack_all(const float* __restrict__ eW1, const float* __restrict__ eW2,
                         const float* __restrict__ eW3, const float* __restrict__ nW1,
                         const float* __restrict__ nW2, const float* __restrict__ nW3,
                         short* __restrict__ dst){
  int o = blockIdx.x*256 + threadIdx.x;
  int seg = o >> 14, rem = o & 16383;
  int kt = rem >> 12, g = (rem >> 10) & 3, n = (rem >> 3) & 127, j = rem & 7;
  int k = kt*32 + g*8 + j;
  const float* src = eW1; int koff = 0;
  switch(seg){
    case 0: src=eW1; koff=0;   break;
    case 1: src=eW1; koff=128; break;
    case 2: src=eW1; koff=256; break;
    case 3: src=eW2; break;
    case 4: src=eW3; break;
    case 5: src=nW1; koff=0;   break;
    case 6: src=nW1; koff=128; break;
    case 7: src=nW2; break;
    case 8: src=nW3; break;
  }
  dst[o] = f2b(src[(size_t)(koff+k)*128 + n]);
}

// ---------------- CSR build (parallel) ----------------
__global__ void k_count(const int* __restrict__ rcv, int* __restrict__ counts){
  int e = blockIdx.x*256 + threadIdx.x;
  if (e < NE) atomicAdd(&counts[rcv[e]], 1);
}
__global__ void k_psum(const int* __restrict__ counts, int* __restrict__ psums){
  __shared__ int red[256];
  int t = threadIdx.x, i = blockIdx.x*256 + t;
  red[t] = (i < NN) ? counts[i] : 0;
  __syncthreads();
  for (int d=128; d; d>>=1){ if (t<d) red[t] += red[t+d]; __syncthreads(); }
  if (!t) psums[blockIdx.x] = red[0];
}
__global__ __launch_bounds__(512) void k_scanp(const int* __restrict__ psums, int* __restrict__ bbase){
  __shared__ int ps[512];
  int t = threadIdx.x;
  int v = (t < SCAN_B) ? psums[t] : 0;
  ps[t] = v; __syncthreads();
  for (int d=1; d<512; d<<=1){
    int x = (t>=d) ? ps[t-d] : 0;
    __syncthreads();
    ps[t] += x;
    __syncthreads();
  }
  if (t < SCAN_B) bbase[t] = ps[t] - v;   // exclusive
}
__global__ void k_local(const int* __restrict__ counts, const int* __restrict__ bbase,
                        int* __restrict__ offsets, int* __restrict__ cursor){
  __shared__ int ps[256];
  int t = threadIdx.x, i = blockIdx.x*256 + t;
  int v = (i < NN) ? counts[i] : 0;
  ps[t] = v; __syncthreads();
  for (int d=1; d<256; d<<=1){
    int x = (t>=d) ? ps[t-d] : 0;
    __syncthreads();
    ps[t] += x;
    __syncthreads();
  }
  int excl = bbase[blockIdx.x] + ps[t] - v;
  if (i < NN){ offsets[i] = excl; cursor[i] = excl; }
  if (i == 0) offsets[NN] = NE;
}
__global__ void k_scatter(const int* __restrict__ rcv, int* __restrict__ cursor,
                          int* __restrict__ pos){
  int e = blockIdx.x*256 + threadIdx.x;
  if (e < NE) pos[e] = atomicAdd(&cursor[rcv[e]], 1);
}

// T[node][0:128]=nodes@W1s, [128:256]=nodes@W1r  (bf16, no bias), vectorized 16B stores
__global__ __launch_bounds__(512,4) void compute_T(
    const float* __restrict__ nodef, const short* __restrict__ wp,
    short* __restrict__ Tt, int nrows)
{
  __shared__ __align__(16) short Ws[16384];   // 32KB: weight, then reused as y-staging
  const int tid=threadIdx.x, lane=tid&63, wid=tid>>6, l16=lane&15, hi=lane>>4;
  const int row0 = blockIdx.x*128;
  const int arow_l = wid*16 + l16;
  const int arow_c = min(row0 + arow_l, nrows-1);
  const float* s = nodef + (size_t)arow_c*128;

  bf16x8 af[4];
  #pragma unroll
  for (int kt=0; kt<4; kt++){
    int ko = kt*32 + hi*8;
    af[kt] = pack_bf8(*(const f32x4*)(s+ko), *(const f32x4*)(s+ko+4));
  }
  int4 w[4];
  #pragma unroll
  for (int i=0;i<4;i++) w[i] = ((const int4*)wp)[tid + 512*i];

  for (int o=0; o<2; o++){
    if (o) __syncthreads();
    #pragma unroll
    for (int i=0;i<4;i++) ((int4*)Ws)[tid + 512*i] = w[i];
    if (o < 1){
      #pragma unroll
      for (int i=0;i<4;i++) w[i] = ((const int4*)(wp + 16384))[tid + 512*i];
    }
    __syncthreads();
    f32x4 acc[8];
    #pragma unroll
    for (int t=0;t<8;t++) acc[t] = (f32x4)(0.0f);
    #pragma unroll
    for (int kt=0;kt<4;kt++){
      #pragma unroll
      for (int t=0;t<8;t++){
        bf16x8 bw = *(const bf16x8*)&Ws[kt*4096 + hi*1024 + (t*16+l16)*8];
        acc[t] = __builtin_amdgcn_mfma_f32_16x16x32_bf16(af[kt], bw, acc[t], 0,0,0);
      }
    }
    __syncthreads();   // all waves done reading Ws; reuse as [128][128] bf16 staging
    #pragma unroll
    for (int t=0;t<8;t++){
      int col = t*16 + l16;
      #pragma unroll
      for (int r=0;r<4;r++){
        int row = wid*16 + hi*4 + r;
        *(short*)((char*)Ws + row*256 + ((col*2) ^ ((row&7)<<4))) = f2b(acc[t][r]);
      }
    }
    // wave-private readback -> 16B stores
    #pragma unroll
    for (int u=0;u<4;u++){
      int q = lane + u*64;
      int r16 = q >> 4, c = q & 15;
      int rl = wid*16 + r16;
      int grow = row0 + rl;
      if (grow < nrows){
        bf16x8 v = *(const bf16x8*)((char*)Ws + rl*256 + ((c*16) ^ ((rl&7)<<4)));
        *(bf16x8*)(Tt + (size_t)grow*256 + o*128 + c*8) = v;
      }
    }
  }
}

// full 32KB weight restage: barrier, write Ws from regs, preload next, barrier
#define WSTAGE(NEXT) do{ __syncthreads(); \
  _Pragma("unroll") for(int i=0;i<4;i++) ((int4*)Ws)[tid + 512*i] = w[i]; \
  if ((NEXT) != nullptr){ _Pragma("unroll") for(int i=0;i<4;i++) w[i] = ((const int4*)(NEXT))[tid + 512*i]; } \
  __syncthreads(); }while(0)

#define MM_G() do{ _Pragma("unroll") for(int kt=0;kt<4;kt++){ \
  _Pragma("unroll") for(int t=0;t<8;t++){ \
    bf16x8 bw = *(const bf16x8*)&Ws[kt*4096 + hi*1024 + (t*16+l16)*8]; \
    acc[t] = __builtin_amdgcn_mfma_f32_16x16x32_bf16(afg[kt], bw, acc[t], 0,0,0);} } }while(0)

#define MM_H() do{ _Pragma("unroll") for(int kt=0;kt<4;kt++){ \
  bf16x8 afv = *(const bf16x8*)((char*)HGs + arow_l*256 + ((kt*64 + hi*16) ^ ((arow_l&7)<<4))); \
  _Pragma("unroll") for(int t=0;t<8;t++){ \
    bf16x8 bw = *(const bf16x8*)&Ws[kt*4096 + hi*1024 + (t*16+l16)*8]; \
    acc[t] = __builtin_amdgcn_mfma_f32_16x16x32_bf16(afv, bw, acc[t], 0,0,0);} } }while(0)

#define EPI_RELU(BP, ADDG) do{ \
  _Pragma("unroll") for (int t=0;t<8;t++){ \
    int col=t*16+l16; float bb=(BP)[col]; \
    _Pragma("unroll") for (int r=0;r<4;r++){ \
      int row=wid*16+hi*4+r; \
      float g=0.0f; \
      if (ADDG) g=b2f(*(const short*)((char*)HGs+row*256+((col*2)^((row&7)<<4)))); \
      float v=fmaxf(acc[t][r]+g+bb,0.0f); \
      *(short*)((char*)HGs+row*256+((col*2)^((row&7)<<4)))=f2b(v); \
      acc[t][r]=0.0f; \
    } } }while(0)

// MODE 0: edge MLP. L1 = edges@W1a + G(T_s[snd]+T_r[rcv]) + b1. out=LN+edge, Ey[pos[e]]=bf16(LN)
// MODE 1: node MLP. L1 = nodes@W1a + agg@W1b + b1; agg = contiguous CSR sum of Ey. out=LN+node
template<int MODE>
__global__ __launch_bounds__(512,4) void gnb_mlp(
    const float* __restrict__ nodef, const float* __restrict__ edgef,
    const int* __restrict__ snd, const int* __restrict__ rcv,
    const int* __restrict__ off, const int* __restrict__ pos,
    const short* __restrict__ Tt, short* __restrict__ Ey,
    const short* __restrict__ W1a, const short* __restrict__ W1b,
    const short* __restrict__ W2, const short* __restrict__ W3,
    const float* __restrict__ b1p, const float* __restrict__ b2p, const float* __restrict__ b3p,
    const float* __restrict__ gmp, const float* __restrict__ btp,
    float* __restrict__ outp, int nrows)
{
  __shared__ __align__(16) short Ws[16384];   // 32KB: one full 128x128 weight, [kt][g][n][j]
  __shared__ __align__(16) short HGs[16384];  // 32KB: [128][128] bf16, XOR-swizzled

  const int tid=threadIdx.x, lane=tid&63, wid=tid>>6, l16=lane&15, hi=lane>>4;
  const int row0 = blockIdx.x*128;
  const int arow_l = wid*16 + l16;
  const int arow_c = min(row0 + arow_l, nrows-1);

  // preload W1a into regs
  int4 w[4];
  #pragma unroll
  for (int i=0;i<4;i++) w[i] = ((const int4*)W1a)[tid + 512*i];

  if (MODE==0){
    // stage G = T_s[snd] + T_r[rcv] into HGs (batched loads; VGPR budget OK at (512,4))
    bf16x8 ga[4], gb[4];
    #pragma unroll
    for (int u=0;u<4;u++){
      int q = tid + u*512, gr = q >> 4, c = q & 15;
      int grow = row0 + gr;                  // exact (NE % 128 == 0)
      int si = snd[grow], ri = rcv[grow];
      ga[u] = *(const bf16x8*)(Tt + (size_t)si*256 + c*8);
      gb[u] = *(const bf16x8*)(Tt + (size_t)ri*256 + 128 + c*8);
    }
    #pragma unroll
    for (int u=0;u<4;u++){
      int q = tid + u*512, gr = q >> 4, c = q & 15;
      bf16x8 o8;
      #pragma unroll
      for (int j=0;j<8;j++) o8[j] = f2b(b2f(ga[u][j]) + b2f(gb[u][j]));
      *(bf16x8*)((char*)HGs + gr*256 + ((c*16) ^ ((gr&7)<<4))) = o8;
    }
  } else {
    // stage agg = contiguous CSR-stream sum of Ey rows
    #pragma unroll
    for (int u=0;u<4;u++){
      int q = tid + u*512, gr = q >> 4, c = q & 15;
      int grow = row0 + gr;
      float s8[8] = {0,0,0,0,0,0,0,0};
      if (grow < nrows){
        int jb = off[grow], je = off[grow+1];
        for (int j=jb;j<je;j++){
          bf16x8 v = *(const bf16x8*)(Ey + (size_t)j*128 + c*8);
          #pragma unroll
          for (int k=0;k<8;k++) s8[k] += b2f(v[k]);
        }
      }
      bf16x8 o8;
      #pragma unroll
      for (int k=0;k<8;k++) o8[k] = f2b(s8[k]);
      *(bf16x8*)((char*)HGs + gr*256 + ((c*16) ^ ((gr&7)<<4))) = o8;
    }
  }

  // stage W1a (barrier also covers G/agg-stage), preload next weight
  WSTAGE((MODE==0) ? W2 : W1b);

  // A-row preload (f32 -> bf16) for layer-1a
  const float* s1 = (MODE==0) ? (edgef + (size_t)arow_c*128) : (nodef + (size_t)arow_c*128);
  bf16x8 afg[4];
  #pragma unroll
  for (int kt=0;kt<4;kt++){
    int ko = kt*32 + hi*8;
    afg[kt] = pack_bf8(*(const f32x4*)(s1+ko), *(const f32x4*)(s1+ko+4));
  }

  f32x4 acc[8];
  #pragma unroll
  for (int t=0;t<8;t++) acc[t] = (f32x4)(0.0f);

  MM_G();                         // layer 1a
  if (MODE==1){
    WSTAGE(W2);                   // W1b in, preload W2
    MM_H();                       // layer 1b: agg @ W1b (HGs holds agg)
  }
  EPI_RELU(b1p, (MODE==0));       // +G (edge) + b1, relu -> HGs
  WSTAGE(W3);                     // W2 in, preload W3
  MM_H();                         // layer 2
  EPI_RELU(b2p, false);
  WSTAGE((const short*)nullptr);  // W3 in
  MM_H();                         // layer 3

  // ---- LayerNorm (in-register) ----
  float ps[4] = {0,0,0,0}, pq[4] = {0,0,0,0};
  #pragma unroll
  for (int t=0;t<8;t++){
    float bb = b3p[t*16+l16];
    #pragma unroll
    for (int r=0;r<4;r++){
      float v = acc[t][r] + bb;
      acc[t][r] = v;
      ps[r] += v; pq[r] += v*v;
    }
  }
  #pragma unroll
  for (int m=1;m<16;m<<=1){
    #pragma unroll
    for (int r=0;r<4;r++){
      ps[r] += __shfl_xor(ps[r], m);
      pq[r] += __shfl_xor(pq[r], m);
    }
  }
  float mu[4], rs[4];
  #pragma unroll
  for (int r=0;r<4;r++){
    mu[r] = ps[r] * (1.0f/128.0f);
    float var = pq[r] * (1.0f/128.0f) - mu[r]*mu[r];
    rs[r] = rsqrtf(var + 1e-5f);
  }

  // y (post-LN, pre-residual) -> HGs bf16 (wave-private rows, no barrier needed)
  #pragma unroll
  for (int t=0;t<8;t++){
    int col = t*16 + l16;
    float gm = gmp[col], be = btp[col];
    #pragma unroll
    for (int r=0;r<4;r++){
      float y = (acc[t][r]-mu[r])*rs[r]*gm + be;
      int row = wid*16 + hi*4 + r;
      *(short*)((char*)HGs + row*256 + ((col*2) ^ ((row&7)<<4))) = f2b(y);
    }
  }

  // coalesced vector epilogue: outp = y + residual (f32x4 stores), Ey 16B CSR scatter
  #pragma unroll
  for (int u=0;u<4;u++){
    int q = lane + u*64;
    int r16 = q >> 4, c = q & 15;
    int rl = wid*16 + r16;
    int grow = row0 + rl;
    bf16x8 v = *(const bf16x8*)((char*)HGs + rl*256 + ((c*16) ^ ((rl&7)<<4)));
    if (MODE==0){
      const float* ef = edgef + (size_t)grow*128 + c*8;
      f32x4 e0 = *(const f32x4*)ef, e1 = *(const f32x4*)(ef+4);
      f32x4 o0, o1;
      #pragma unroll
      for (int j=0;j<4;j++){ o0[j] = b2f(v[j]) + e0[j]; o1[j] = b2f(v[j+4]) + e1[j]; }
      float* op = outp + (size_t)grow*128 + c*8;
      *(f32x4*)op = o0; *(f32x4*)(op+4) = o1;
      int p = pos[grow];
      *(bf16x8*)(Ey + (size_t)p*128 + c*8) = v;
    } else {
      if (grow < nrows){
        const float* nf = nodef + (size_t)grow*128 + c*8;
        f32x4 e0 = *(const f32x4*)nf, e1 = *(const f32x4*)(nf+4);
        f32x4 o0, o1;
        #pragma unroll
        for (int j=0;j<4;j++){ o0[j] = b2f(v[j]) + e0[j]; o1[j] = b2f(v[j+4]) + e1[j]; }
        float* op = outp + (size_t)grow*128 + c*8;
        *(f32x4*)op = o0; *(f32x4*)(op+4) = o1;
      }
    }
  }
}

extern "C" void kernel_launch(void* const* d_in, const int* in_sizes, int n_in,
                              void* d_out, int out_size, void* d_ws, size_t ws_size,
                              hipStream_t stream)
{
  (void)in_sizes; (void)n_in; (void)out_size; (void)ws_size;
  const float* nodef = (const float*)d_in[0];
  const float* edgef = (const float*)d_in[1];
  const int*   snd   = (const int*)d_in[2];
  const int*   rcv   = (const int*)d_in[3];
  const float* eW1 = (const float*)d_in[4];
  const float* eb1 = (const float*)d_in[5];
  const float* eW2 = (const float*)d_in[6];
  const float* eb2 = (const float*)d_in[7];
  const float* eW3 = (const float*)d_in[8];
  const float* eb3 = (const float*)d_in[9];
  const float* egm = (const float*)d_in[10];
  const float* ebt = (const float*)d_in[11];
  const float* nW1 = (const float*)d_in[12];
  const float* nb1 = (const float*)d_in[13];
  const float* nW2 = (const float*)d_in[14];
  const float* nb2 = (const float*)d_in[15];
  const float* nW3 = (const float*)d_in[16];
  const float* nb3 = (const float*)d_in[17];
  const float* ngm = (const float*)d_in[18];
  const float* nbt = (const float*)d_in[19];

  char* wsb = (char*)d_ws;
  short* Tt = (short*)wsb;                               // NN*256*2
  short* Ey = (short*)(wsb + (size_t)NN*256*2);          // NE*128*2
  int* counts  = (int*)(wsb + (size_t)NN*256*2 + (size_t)NE*128*2);
  int* offsets = counts + NN;                            // NN+1
  int* cursor  = offsets + NN + 8;
  int* psums   = cursor + NN;                            // 512
  int* bbase   = psums + 512;                            // 512
  int* pos     = bbase + 512;                            // NE
  short* wp    = (short*)(pos + NE);                     // 9*16384 shorts

  hipMemsetAsync(counts, 0, (size_t)NN*4, stream);
  k_count<<<(NE+255)/256,256,0,stream>>>(rcv, counts);
  k_psum<<<SCAN_B,256,0,stream>>>(counts, psums);
  k_scanp<<<1,512,0,stream>>>(psums, bbase);
  k_local<<<SCAN_B,256,0,stream>>>(counts, bbase, offsets, cursor);
  k_scatter<<<(NE+255)/256,256,0,stream>>>(rcv, cursor, pos);

  pack_all<<<576,256,0,stream>>>(eW1,eW2,eW3,nW1,nW2,nW3,wp);
  compute_T<<<(NN+127)/128,512,0,stream>>>(nodef, wp, Tt, NN);

  float* out_nodes = (float*)d_out;
  float* out_edges = out_nodes + (size_t)NN*128;

  gnb_mlp<0><<<NE/128,512,0,stream>>>(nodef, edgef, snd, rcv, offsets, pos, Tt, Ey,
      wp+2*16384, (const short*)nullptr, wp+3*16384, wp+4*16384,
      eb1,eb2,eb3, egm,ebt, out_edges, NE);
  gnb_mlp<1><<<(NN+127)/128,512,0,stream>>>(nodef, edgef, snd, rcv, offsets, pos, Tt, Ey,
      wp+5*16384, wp+6*16384, wp+7*16384, wp+8*16384,
      nb1,nb2,nb3, ngm,nbt, out_nodes, NN);
}